// Round 1
// baseline (542.571 us; speedup 1.0000x reference)
//
#include <hip/hip_runtime.h>
#include <stdint.h>

#define B_    32
#define D_    256
#define HW_   1024
#define N_    32768      // B_*HW_
#define K_    1024
#define BETA_ 0.25f

// ---- workspace layout (bytes) ----
#define PACK_OFF   0           // N_ * 8  (u64: key<<32 | k), init 0xFF
#define ENORM_OFF  262144      // K_ floats
#define SUMED_OFF  266240      // 256 floats (col sums of E)
#define SUMZD_OFF  267264      // 256 floats (per-d sums of Z)
#define CNT_OFF    268288      // K_ u32
#define SCAL_OFF   272384      // 4 floats: [0]=sum_e2 [1]=sum_z2 [2]=sum_diff2
#define ZERO_OFF   SUMED_OFF
#define ZERO_BYTES (272400 - SUMED_OFF)

__device__ __forceinline__ float blockReduceSum(float v, volatile float* sred) {
  #pragma unroll
  for (int off = 32; off > 0; off >>= 1) v += __shfl_down(v, off, 64);
  __syncthreads();
  if ((threadIdx.x & 63) == 0) sred[threadIdx.x >> 6] = v;
  __syncthreads();
  float r = 0.0f;
  if (threadIdx.x == 0) {
    const int nw = blockDim.x >> 6;
    for (int i = 0; i < nw; ++i) r += sred[i];
  }
  return r;  // valid on thread 0 only
}

// enorm[k] = sum_d e[k,d]^2 ; sum_e2 ; column sums sum_e_d[d]
__global__ void vq_e_stats(const float* __restrict__ e, float* __restrict__ enorm,
                           float* __restrict__ sum_e_d, float* __restrict__ scal) {
  __shared__ float sred[4];
  const int t = threadIdx.x;
  const int k0 = blockIdx.x * 16;      // 64 blocks x 16 k
  float col = 0.0f;
  float e2tot = 0.0f;
  for (int kk = 0; kk < 16; ++kk) {
    const float v = e[(k0 + kk) * D_ + t];
    col += v;
    const float s = blockReduceSum(v * v, sred);
    if (t == 0) { enorm[k0 + kk] = s; e2tot += s; }
    __syncthreads();
  }
  atomicAdd(&sum_e_d[t], col);
  if (t == 0) atomicAdd(&scal[0], e2tot);
}

// per-d sums of z and total sum z^2.  grid = B_*D_ blocks (one per (b,d) row of 1024)
__global__ void vq_z_stats(const float* __restrict__ z, float* __restrict__ sum_z_d,
                           float* __restrict__ scal) {
  __shared__ float sred[4];
  const int bd = blockIdx.x;
  const float* p = z + (size_t)bd * HW_;
  const int t = threadIdx.x;
  float s = 0.0f, s2 = 0.0f;
  #pragma unroll
  for (int i = 0; i < 4; ++i) {
    const float v = p[t + 256 * i];
    s += v; s2 += v * v;
  }
  const float rs = blockReduceSum(s, sred);
  __syncthreads();
  const float rs2 = blockReduceSum(s2, sred);
  if (t == 0) {
    atomicAdd(&sum_z_d[bd & 255], rs);
    atomicAdd(&scal[1], rs2);
  }
}

__device__ __forceinline__ unsigned long long pack64(float v, int k) {
  unsigned int b = __float_as_uint(v);
  b = (b & 0x80000000u) ? ~b : (b | 0x80000000u);   // order-preserving map
  return ((unsigned long long)b << 32) | (unsigned int)k;
}

// main kernel: for each n, argmin_k ( enorm[k] - 2 * z_n . e_k )
// grid = 512: (ntile 0..255) x (ksplit 0..1).  NT=128 n, k-range 512 per block,
// k-tiles of 128, 8x8 micro-tile per thread (16x16 thread grid).
__global__ __launch_bounds__(256, 2)
void vq_argmin(const float* __restrict__ z, const float* __restrict__ e,
               const float* __restrict__ enorm, unsigned long long* __restrict__ packArr) {
  union SM {
    struct { float As[16][132]; float Bs[16][128]; } t;   // 16640 B
    unsigned long long red[16][128];                      // 16384 B
  };
  __shared__ SM sm;

  const int bx = blockIdx.x;
  const int ntile = bx >> 1;
  const int ks    = bx & 1;
  const int b   = ntile >> 3;
  const int hw0 = (ntile & 7) << 7;     // 128 n per tile
  const int t  = threadIdx.x;
  const int tx = t & 15;                // n group (8 each)
  const int ty = t >> 4;                // k group (8 each)
  const float* zb = z + (size_t)b * D_ * HW_ + hw0;

  float bestv[8];
  int   bestk[8];
  #pragma unroll
  for (int j = 0; j < 8; ++j) { bestv[j] = 3.0e38f; bestk[j] = 0; }

  for (int kt = 0; kt < 4; ++kt) {
    const int kbase = ks * 512 + kt * 128;
    float acc[8][8];
    #pragma unroll
    for (int i = 0; i < 8; ++i)
      #pragma unroll
      for (int j = 0; j < 8; ++j) acc[i][j] = 0.0f;

    for (int dc = 0; dc < 16; ++dc) {
      const int d0 = dc * 16;
      // stage E-tile transposed: As[dd][k]  (128 k x 16 d -> 512 float4)
      #pragma unroll
      for (int r = 0; r < 2; ++r) {
        const int j = r * 256 + t;
        const int krow = j >> 2;             // 0..127
        const int dseg = (j & 3) << 2;       // 0,4,8,12
        const float4 f = *(const float4*)(e + (size_t)(kbase + krow) * D_ + d0 + dseg);
        sm.t.As[dseg + 0][krow] = f.x;
        sm.t.As[dseg + 1][krow] = f.y;
        sm.t.As[dseg + 2][krow] = f.z;
        sm.t.As[dseg + 3][krow] = f.w;
      }
      // stage Z-tile: Bs[dd][n]  (16 d x 128 n, rows are contiguous in global)
      #pragma unroll
      for (int r = 0; r < 2; ++r) {
        const int j = r * 256 + t;
        const int dd = j >> 5;               // 0..15
        const int c4 = (j & 31) << 2;        // 0..124
        *(float4*)(&sm.t.Bs[dd][c4]) = *(const float4*)(zb + (size_t)(d0 + dd) * HW_ + c4);
      }
      __syncthreads();
      #pragma unroll
      for (int dd = 0; dd < 16; ++dd) {
        const float4 a0 = *(const float4*)&sm.t.As[dd][ty * 8];
        const float4 a1 = *(const float4*)&sm.t.As[dd][ty * 8 + 4];
        const float4 b0 = *(const float4*)&sm.t.Bs[dd][tx * 8];
        const float4 b1 = *(const float4*)&sm.t.Bs[dd][tx * 8 + 4];
        const float av[8] = {a0.x, a0.y, a0.z, a0.w, a1.x, a1.y, a1.z, a1.w};
        const float bv[8] = {b0.x, b0.y, b0.z, b0.w, b1.x, b1.y, b1.z, b1.w};
        #pragma unroll
        for (int i = 0; i < 8; ++i)
          #pragma unroll
          for (int j = 0; j < 8; ++j)
            acc[i][j] = fmaf(av[i], bv[j], acc[i][j]);
      }
      __syncthreads();
    }
    // fold this k-tile into the running per-thread argmin
    #pragma unroll
    for (int i = 0; i < 8; ++i) {
      const int k = kbase + ty * 8 + i;
      const float en = enorm[k];
      #pragma unroll
      for (int j = 0; j < 8; ++j) {
        const float v = fmaf(-2.0f, acc[i][j], en);
        if (v < bestv[j]) { bestv[j] = v; bestk[j] = k; }  // ascending k => first-min tiebreak
      }
    }
    __syncthreads();
  }

  // cross-thread (ty) reduce per n, then global atomicMin merge across ksplit blocks
  #pragma unroll
  for (int j = 0; j < 8; ++j) sm.red[ty][tx * 8 + j] = pack64(bestv[j], bestk[j]);
  __syncthreads();
  if (t < 128) {
    unsigned long long m = sm.red[0][t];
    #pragma unroll
    for (int i = 1; i < 16; ++i) {
      const unsigned long long c = sm.red[i][t];
      if (c < m) m = c;
    }
    atomicMin(&packArr[(size_t)b * HW_ + hw0 + t], m);
  }
}

// gather z_q -> out (NCHW), accumulate sum (z_q - z)^2, histogram counts.
// grid = 512 (B*HW/64), 256 threads: 64 n x 4 d-groups of 64 d.
__global__ void vq_gather(const float* __restrict__ z, const float* __restrict__ e,
                          const unsigned long long* __restrict__ packArr,
                          float* __restrict__ out, unsigned int* __restrict__ counts,
                          float* __restrict__ scal) {
  __shared__ float sred[4];
  const int t   = threadIdx.x;
  const int blk = blockIdx.x;
  const int b   = blk >> 4;
  const int hw0 = (blk & 15) << 6;
  const int nl  = t >> 2;               // 0..63
  const int dg  = t & 3;                // d-group of 64
  const int hw  = hw0 + nl;
  const unsigned int k = (unsigned int)(packArr[(size_t)b * HW_ + hw] & 0xFFFFFFFFull);
  if (dg == 0) atomicAdd(&counts[k], 1u);

  const float4* ep = (const float4*)(e + (size_t)k * D_ + dg * 64);
  const size_t base = ((size_t)(b * D_ + dg * 64)) * HW_ + hw;
  float* op = out + base;
  const float* zp = z + base;

  float s2 = 0.0f;
  #pragma unroll
  for (int i = 0; i < 16; ++i) {
    const float4 f = ep[i];
    const float vv[4] = {f.x, f.y, f.z, f.w};
    #pragma unroll
    for (int c = 0; c < 4; ++c) {
      const size_t off = (size_t)(i * 4 + c) * HW_;
      const float zv = zp[off];
      op[off] = vv[c];
      const float df = vv[c] - zv;
      s2 = fmaf(df, df, s2);
    }
  }
  const float rs = blockReduceSum(s2, sred);
  if (t == 0) atomicAdd(&scal[2], rs);
}

// single block: loss, perplexity, mean_distance
__global__ void vq_final(const unsigned int* __restrict__ counts,
                         const float* __restrict__ sum_e_d, const float* __restrict__ sum_z_d,
                         const float* __restrict__ scal, float* __restrict__ out) {
  __shared__ float sred[4];
  const int t = threadIdx.x;
  float h = 0.0f;
  for (int i = t; i < K_; i += 256) {
    const float em = (float)counts[i] * (1.0f / (float)N_);
    h += em * logf(em + 1e-10f);
  }
  const float hs = blockReduceSum(h, sred);
  __syncthreads();
  const float dv = sum_z_d[t] * sum_e_d[t];
  const float dot = blockReduceSum(dv, sred);
  if (t == 0) {
    const float loss = (1.0f + BETA_) * scal[2] / (float)(N_ * D_);
    const float perp = expf(-hs);
    const float md = scal[1] / (float)N_ + scal[0] / (float)K_
                   - 2.0f * dot / ((float)N_ * (float)K_);
    out[(size_t)N_ * D_ + 0] = loss;
    out[(size_t)N_ * D_ + 1] = perp;
    out[(size_t)N_ * D_ + 2] = md;
  }
}

extern "C" void kernel_launch(void* const* d_in, const int* in_sizes, int n_in,
                              void* d_out, int out_size, void* d_ws, size_t ws_size,
                              hipStream_t stream) {
  const float* z = (const float*)d_in[0];        // [32,256,32,32]
  const float* e = (const float*)d_in[1];        // [1024,256]
  float* out = (float*)d_out;

  char* ws = (char*)d_ws;
  unsigned long long* packArr = (unsigned long long*)(ws + PACK_OFF);
  float* enorm   = (float*)(ws + ENORM_OFF);
  float* sum_e_d = (float*)(ws + SUMED_OFF);
  float* sum_z_d = (float*)(ws + SUMZD_OFF);
  unsigned int* counts = (unsigned int*)(ws + CNT_OFF);
  float* scal    = (float*)(ws + SCAL_OFF);

  hipMemsetAsync(ws + PACK_OFF, 0xFF, (size_t)N_ * 8, stream);
  hipMemsetAsync(ws + ZERO_OFF, 0x00, (size_t)ZERO_BYTES, stream);

  vq_e_stats<<<dim3(64), dim3(256), 0, stream>>>(e, enorm, sum_e_d, scal);
  vq_z_stats<<<dim3(B_ * D_), dim3(256), 0, stream>>>(z, sum_z_d, scal);
  vq_argmin<<<dim3(512), dim3(256), 0, stream>>>(z, e, enorm, packArr);
  vq_gather<<<dim3(512), dim3(256), 0, stream>>>(z, e, packArr, out, counts, scal);
  vq_final<<<dim3(1), dim3(256), 0, stream>>>(counts, sum_e_d, sum_z_d, scal, out);
}

// Round 2
// 220.245 us; speedup vs baseline: 2.4635x; 2.4635x over previous
//
#include <hip/hip_runtime.h>
#include <stdint.h>

#define B_    32
#define D_    256
#define HW_   1024
#define N_    32768      // B_*HW_
#define K_    1024
#define BETA_ 0.25f
#define OUT0  8388608    // N_*D_

typedef short bf16x8 __attribute__((ext_vector_type(8)));
typedef short s16x4  __attribute__((ext_vector_type(4)));
typedef float f32x4  __attribute__((ext_vector_type(4)));

// ---- workspace layout (bytes) ----
#define E2H_OFF   0          // 512 KB  bf16 hi of E, fragment order
#define E2L_OFF   524288     // 512 KB  bf16 lo of E, fragment order
#define ENORM_OFF 1048576    // 4 KB    ||e_k||^2 fp32
#define IDX_OFF   1052672    // 128 KB  argmin index per n (u32)
#define SUMED_OFF 1183744    // 1 KB    col sums of E (fp32)
#define SUMZD_OFF 1184768    // 1 KB    per-d sums of Z (fp32)
#define CNT_OFF   1185792    // 4 KB    histogram (u32)
#define SCAL_OFF  1189888    // 32 B    doubles: [1]=sum z^2, [2]=sum diff^2
#define ZERO_OFF  SUMED_OFF
#define ZERO_BYTES (1189920 - SUMED_OFF)

__device__ __forceinline__ unsigned short f2bf(float f) {
  unsigned int u = __float_as_uint(f);
  u += 0x7FFFu + ((u >> 16) & 1u);          // round-to-nearest-even
  return (unsigned short)(u >> 16);
}

__device__ __forceinline__ unsigned long long pack64(float v, int k) {
  unsigned int b = __float_as_uint(v);
  b = (b & 0x80000000u) ? ~b : (b | 0x80000000u);   // order-preserving map
  return ((unsigned long long)b << 32) | (unsigned int)k;
}

__device__ __forceinline__ float blockReduceSum(float v, volatile float* sred) {
  #pragma unroll
  for (int off = 32; off > 0; off >>= 1) v += __shfl_down(v, off, 64);
  __syncthreads();
  if ((threadIdx.x & 63) == 0) sred[threadIdx.x >> 6] = v;
  __syncthreads();
  float r = 0.0f;
  if (threadIdx.x == 0) {
    const int nw = blockDim.x >> 6;
    for (int i = 0; i < nw; ++i) r += sred[i];
  }
  return r;  // valid on thread 0 only
}

// ---------------------------------------------------------------------------
// E prep: fragment-ordered bf16 hi/lo of E, enorm[k], column sums of E.
// grid 64 x 512 threads. Block kt handles codes [kt*16, kt*16+16).
// Fragment order: E2h[((ds*64 + kt)*64 + lane)*8 + j]  (16k x 32d A-tiles,
// lane -> (m=lane&15, d=(lane>>4)*8+j) matching mfma_f32_16x16x32 A layout).
// ---------------------------------------------------------------------------
__global__ void vq_eprep(const float* __restrict__ e, unsigned short* __restrict__ E2h,
                         unsigned short* __restrict__ E2l, float* __restrict__ enorm,
                         float* __restrict__ sum_e_d) {
  __shared__ float ered[16][33];
  __shared__ float sumed[256];
  const int t  = threadIdx.x;
  const int kt = blockIdx.x;
  const int ds = t >> 6, l = t & 63;
  const int q  = l >> 4, m = l & 15;
  const int k  = kt * 16 + m;
  const int d0 = ds * 32 + q * 8;
  if (t < 256) sumed[t] = 0.0f;
  __syncthreads();

  const float* ep = e + (size_t)k * D_ + d0;
  const float4 v0 = *(const float4*)ep;
  const float4 v1 = *(const float4*)(ep + 4);
  const float vv[8] = {v0.x, v0.y, v0.z, v0.w, v1.x, v1.y, v1.z, v1.w};
  short hv[8], lv[8];
  float p = 0.0f;
  #pragma unroll
  for (int j = 0; j < 8; ++j) {
    const float f = vv[j];
    p += f * f;
    const unsigned short h = f2bf(f);
    hv[j] = (short)h;
    const float hf = __uint_as_float((unsigned int)h << 16);
    lv[j] = (short)f2bf(f - hf);
    atomicAdd(&sumed[d0 + j], f);
  }
  const size_t fi = ((size_t)(ds * 64 + kt)) * 64 + l;
  *(bf16x8*)(E2h + fi * 8) = *(bf16x8*)hv;
  *(bf16x8*)(E2l + fi * 8) = *(bf16x8*)lv;

  ered[m][ds * 4 + q] = p;
  __syncthreads();
  if (t < 16) {
    float s = 0.0f;
    #pragma unroll
    for (int i = 0; i < 32; ++i) s += ered[t][i];
    enorm[kt * 16 + t] = s;
  }
  if (t < 256) atomicAdd(&sum_e_d[t], sumed[t]);
}

// ---------------------------------------------------------------------------
// Main argmin kernel. grid 512 x 512 threads, 1 block/CU (LDS ~25 KB, VGPR~220).
// Block = 64 n (one b, hw0..hw0+63) x ALL 1024 k.  8 waves, wave w owns
// k in [w*128, w*128+128).  3-term bf16 split MFMA, d double-buffered in LDS.
// Fused: per-d z sums (LDS atomics) + sum z^2 (double atomic).
// ---------------------------------------------------------------------------
__global__ __launch_bounds__(512, 2)
void vq_argmin2(const float* __restrict__ z,
                const unsigned short* __restrict__ E2h, const unsigned short* __restrict__ E2l,
                const float* __restrict__ enorm_g,
                unsigned int* __restrict__ idx, unsigned int* __restrict__ counts,
                float* __restrict__ sum_z_d, double* __restrict__ scald) {
  __shared__ unsigned short Zh[2][2048];   // per buf: 4 ntiles x 64 lanes x 8 bf16
  __shared__ unsigned short Zl[2][2048];
  __shared__ float en[1024];
  __shared__ unsigned long long red[8][64];
  __shared__ float sumzd[256];

  const int t  = threadIdx.x;
  const int nt = blockIdx.x;
  const int b   = nt >> 4;
  const int hw0 = (nt & 15) << 6;
  const int w = t >> 6, l = t & 63;
  const int quad = l >> 4;

  // staging identity: thread stages slot = t&255, j-half = t>>8
  const int slot = t & 255;
  const int jh   = t >> 8;                  // 0 or 1 -> j = jh*4 + c
  const int squad = (slot >> 4) & 3;
  const int nloc  = ((slot >> 6) << 4) + (slot & 15);   // ntile*16 + (slot&15)
  const float* zb = z + ((size_t)b * D_) * HW_ + hw0 + nloc;

  const bf16x8* __restrict__ Eh8 = (const bf16x8*)E2h;
  const bf16x8* __restrict__ El8 = (const bf16x8*)E2l;

  if (t < 256) sumzd[t] = 0.0f;
  en[t] = enorm_g[t];
  en[t + 512] = enorm_g[t + 512];
  __syncthreads();   // sumzd zeroed before any staging atomics

  float zv[4];
  float s2 = 0.0f;

  // ---- prologue: stage dstep 0 into buf 0 ----
  {
    const int dbase = squad * 8 + jh * 4;
    #pragma unroll
    for (int c = 0; c < 4; ++c) zv[c] = zb[(size_t)(dbase + c) * HW_];
    short hv[4], lv[4];
    #pragma unroll
    for (int c = 0; c < 4; ++c) {
      const float f = zv[c];
      s2 = fmaf(f, f, s2);
      atomicAdd(&sumzd[dbase + c], f);
      const unsigned short h = f2bf(f);
      hv[c] = (short)h;
      lv[c] = (short)f2bf(f - __uint_as_float((unsigned int)h << 16));
    }
    *(s16x4*)&Zh[0][slot * 8 + jh * 4] = *(s16x4*)hv;
    *(s16x4*)&Zl[0][slot * 8 + jh * 4] = *(s16x4*)lv;
  }

  f32x4 acc[8][4];
  #pragma unroll
  for (int g = 0; g < 8; ++g)
    #pragma unroll
    for (int ni = 0; ni < 4; ++ni) acc[g][ni] = (f32x4)0.0f;

  for (int ds = 0; ds < 8; ++ds) {
    __syncthreads();                        // buf[ds&1] ready; buf[(ds+1)&1] free
    const int buf = ds & 1;
    if (ds < 7) {                           // prefetch next d-step from global
      const int dbase = (ds + 1) * 32 + squad * 8 + jh * 4;
      #pragma unroll
      for (int c = 0; c < 4; ++c) zv[c] = zb[(size_t)(dbase + c) * HW_];
    }
    // ---- compute on buf ----
    #pragma unroll
    for (int half = 0; half < 2; ++half) {
      bf16x8 Ah[4], Al[4];
      const int ktb = w * 8 + half * 4;
      #pragma unroll
      for (int mi = 0; mi < 4; ++mi) {
        const size_t fi = ((size_t)(ds * 64 + ktb + mi)) * 64 + l;
        Ah[mi] = Eh8[fi];
        Al[mi] = El8[fi];
      }
      #pragma unroll
      for (int ni = 0; ni < 4; ++ni) {
        const bf16x8 Bh = *(const bf16x8*)&Zh[buf][(ni * 64 + l) * 8];
        const bf16x8 Bl = *(const bf16x8*)&Zl[buf][(ni * 64 + l) * 8];
        #pragma unroll
        for (int mi = 0; mi < 4; ++mi) {
          f32x4 a = acc[half * 4 + mi][ni];
          a = __builtin_amdgcn_mfma_f32_16x16x32_bf16(Ah[mi], Bh, a, 0, 0, 0);
          a = __builtin_amdgcn_mfma_f32_16x16x32_bf16(Ah[mi], Bl, a, 0, 0, 0);
          a = __builtin_amdgcn_mfma_f32_16x16x32_bf16(Al[mi], Bh, a, 0, 0, 0);
          acc[half * 4 + mi][ni] = a;
        }
      }
    }
    // ---- write next buf ----
    if (ds < 7) {
      const int dbase = (ds + 1) * 32 + squad * 8 + jh * 4;
      short hv[4], lv[4];
      #pragma unroll
      for (int c = 0; c < 4; ++c) {
        const float f = zv[c];
        s2 = fmaf(f, f, s2);
        atomicAdd(&sumzd[dbase + c], f);
        const unsigned short h = f2bf(f);
        hv[c] = (short)h;
        lv[c] = (short)f2bf(f - __uint_as_float((unsigned int)h << 16));
      }
      *(s16x4*)&Zh[buf ^ 1][slot * 8 + jh * 4] = *(s16x4*)hv;
      *(s16x4*)&Zl[buf ^ 1][slot * 8 + jh * 4] = *(s16x4*)lv;
    }
  }

  __syncthreads();   // all compute + LDS stat atomics done
  if (t < 256) atomicAdd(&sum_z_d[t], sumzd[t]);
  {
    float s2w = s2;
    #pragma unroll
    for (int off = 32; off > 0; off >>= 1) s2w += __shfl_down(s2w, off, 64);
    if (l == 0) atomicAdd(&scald[1], (double)s2w);
  }

  // ---- epilogue: fold enorm - 2S, reduce to per-n argmin ----
  #pragma unroll
  for (int ni = 0; ni < 4; ++ni) {
    float bv = 3.0e38f;
    int   bk = 0;
    #pragma unroll
    for (int g = 0; g < 8; ++g) {
      const f32x4 a = acc[g][ni];
      #pragma unroll
      for (int r = 0; r < 4; ++r) {
        const int k = w * 128 + g * 16 + quad * 4 + r;
        const float v = fmaf(-2.0f, a[r], en[k]);
        if (v < bv) { bv = v; bk = k; }     // k ascending => first-min tiebreak
      }
    }
    unsigned long long p = pack64(bv, bk);
    unsigned long long p2 = __shfl_down(p, 32, 64); if (p2 < p) p = p2;
    p2 = __shfl_down(p, 16, 64);                    if (p2 < p) p = p2;
    if (quad == 0) red[w][ni * 16 + (l & 15)] = p;
  }
  __syncthreads();
  if (t < 64) {
    unsigned long long m = red[0][t];
    #pragma unroll
    for (int i = 1; i < 8; ++i) { const unsigned long long c = red[i][t]; if (c < m) m = c; }
    const unsigned int k = (unsigned int)(m & 0xFFFFFFFFull);
    idx[(size_t)b * HW_ + hw0 + t] = k;
    atomicAdd(&counts[k], 1u);
  }
}

// ---------------------------------------------------------------------------
// gather z_q -> out (NCHW), accumulate sum (z_q - z)^2.
// grid 512 x 256: 64 n x 4 d-groups of 64 d.
// ---------------------------------------------------------------------------
__global__ void vq_gather(const float* __restrict__ z, const float* __restrict__ e,
                          const unsigned int* __restrict__ idx,
                          float* __restrict__ out, double* __restrict__ scald) {
  __shared__ float sred[4];
  const int t   = threadIdx.x;
  const int blk = blockIdx.x;
  const int b   = blk >> 4;
  const int hw0 = (blk & 15) << 6;
  const int nl  = t >> 2;
  const int dg  = t & 3;
  const int hw  = hw0 + nl;
  const unsigned int k = idx[(size_t)b * HW_ + hw];

  const float4* ep = (const float4*)(e + (size_t)k * D_ + dg * 64);
  const size_t base = ((size_t)(b * D_ + dg * 64)) * HW_ + hw;
  float* op = out + base;
  const float* zp = z + base;

  float s2 = 0.0f;
  #pragma unroll
  for (int i = 0; i < 16; ++i) {
    const float4 f = ep[i];
    const float vv[4] = {f.x, f.y, f.z, f.w};
    #pragma unroll
    for (int c = 0; c < 4; ++c) {
      const size_t off = (size_t)(i * 4 + c) * HW_;
      const float zv = zp[off];
      op[off] = vv[c];
      const float df = vv[c] - zv;
      s2 = fmaf(df, df, s2);
    }
  }
  const float rs = blockReduceSum(s2, sred);
  if (t == 0) atomicAdd(&scald[2], (double)rs);
}

// ---------------------------------------------------------------------------
// finalize: loss, perplexity, mean_distance
// ---------------------------------------------------------------------------
__global__ void vq_final(const unsigned int* __restrict__ counts,
                         const float* __restrict__ enorm,
                         const float* __restrict__ sum_e_d, const float* __restrict__ sum_z_d,
                         const double* __restrict__ scald, float* __restrict__ out) {
  __shared__ float sred[4];
  const int t = threadIdx.x;
  float h = 0.0f;
  for (int i = t; i < K_; i += 256) {
    const float em = (float)counts[i] * (1.0f / (float)N_);
    h += em * logf(em + 1e-10f);
  }
  const float hs = blockReduceSum(h, sred);
  __syncthreads();
  const float dv = sum_z_d[t] * sum_e_d[t];
  const float dot = blockReduceSum(dv, sred);
  __syncthreads();
  float e2 = 0.0f;
  #pragma unroll
  for (int i = 0; i < 4; ++i) e2 += enorm[t + 256 * i];
  const float sume2 = blockReduceSum(e2, sred);
  if (t == 0) {
    const double loss = (double)(1.0f + BETA_) * scald[2] / (double)((size_t)N_ * D_);
    const float perp = expf(-hs);
    const double md = scald[1] / (double)N_ + (double)sume2 / (double)K_
                    - 2.0 * (double)dot / ((double)N_ * (double)K_);
    out[OUT0 + 0] = (float)loss;
    out[OUT0 + 1] = perp;
    out[OUT0 + 2] = (float)md;
  }
}

extern "C" void kernel_launch(void* const* d_in, const int* in_sizes, int n_in,
                              void* d_out, int out_size, void* d_ws, size_t ws_size,
                              hipStream_t stream) {
  const float* z = (const float*)d_in[0];        // [32,256,32,32]
  const float* e = (const float*)d_in[1];        // [1024,256]
  float* out = (float*)d_out;

  char* ws = (char*)d_ws;
  unsigned short* E2h = (unsigned short*)(ws + E2H_OFF);
  unsigned short* E2l = (unsigned short*)(ws + E2L_OFF);
  float* enorm   = (float*)(ws + ENORM_OFF);
  unsigned int* idx = (unsigned int*)(ws + IDX_OFF);
  float* sum_e_d = (float*)(ws + SUMED_OFF);
  float* sum_z_d = (float*)(ws + SUMZD_OFF);
  unsigned int* counts = (unsigned int*)(ws + CNT_OFF);
  double* scald  = (double*)(ws + SCAL_OFF);

  hipMemsetAsync(ws + ZERO_OFF, 0x00, (size_t)ZERO_BYTES, stream);

  vq_eprep  <<<dim3(64),  dim3(512), 0, stream>>>(e, E2h, E2l, enorm, sum_e_d);
  vq_argmin2<<<dim3(512), dim3(512), 0, stream>>>(z, E2h, E2l, enorm, idx, counts,
                                                  sum_z_d, scald);
  vq_gather <<<dim3(512), dim3(256), 0, stream>>>(z, e, idx, out, scald);
  vq_final  <<<dim3(1),   dim3(256), 0, stream>>>(counts, enorm, sum_e_d, sum_z_d,
                                                  scald, out);
}

// Round 3
// 210.219 us; speedup vs baseline: 2.5810x; 1.0477x over previous
//
#include <hip/hip_runtime.h>
#include <stdint.h>

#define B_    32
#define D_    256
#define HW_   1024
#define N_    32768      // B_*HW_
#define K_    1024
#define BETA_ 0.25f
#define OUT0  8388608    // N_*D_

typedef short bf16x8 __attribute__((ext_vector_type(8)));
typedef short s16x4  __attribute__((ext_vector_type(4)));
typedef float f32x4  __attribute__((ext_vector_type(4)));

// ---- workspace layout (bytes) ----
#define E2H_OFF   0          // 512 KB  bf16 hi of E, fragment order
#define E2L_OFF   524288     // 512 KB  bf16 lo of E, fragment order
#define ENORM_OFF 1048576    // 4 KB    ||e_k||^2 fp32
#define SUMED_OFF 1052672    // 1 KB    col sums of E (fp32)
#define SUMZD_OFF 1053696    // 1 KB    per-d sums of Z (fp32)
#define CNT_OFF   1054720    // 4 KB    histogram (u32)
#define SCAL_OFF  1058816    // 32 B    doubles: [1]=sum z^2, [2]=sum diff^2
#define ZERO_OFF  SUMED_OFF
#define ZERO_BYTES (1058848 - SUMED_OFF)

__device__ __forceinline__ unsigned short f2bf(float f) {
  unsigned int u = __float_as_uint(f);
  u += 0x7FFFu + ((u >> 16) & 1u);          // round-to-nearest-even
  return (unsigned short)(u >> 16);
}

__device__ __forceinline__ unsigned long long pack64(float v, int k) {
  unsigned int b = __float_as_uint(v);
  b = (b & 0x80000000u) ? ~b : (b | 0x80000000u);   // order-preserving map
  return ((unsigned long long)b << 32) | (unsigned int)k;
}

__device__ __forceinline__ float unpack32(unsigned int p) {
  p = (p & 0x80000000u) ? (p ^ 0x80000000u) : ~p;   // inverse of pack's key map
  return __uint_as_float(p);
}

__device__ __forceinline__ float blockReduceSum(float v, volatile float* sred) {
  #pragma unroll
  for (int off = 32; off > 0; off >>= 1) v += __shfl_down(v, off, 64);
  __syncthreads();
  if ((threadIdx.x & 63) == 0) sred[threadIdx.x >> 6] = v;
  __syncthreads();
  float r = 0.0f;
  if (threadIdx.x == 0) {
    const int nw = blockDim.x >> 6;
    for (int i = 0; i < nw; ++i) r += sred[i];
  }
  return r;  // valid on thread 0 only
}

// ---------------------------------------------------------------------------
// E prep: fragment-ordered bf16 hi/lo of E, enorm[k], column sums of E.
// grid 64 x 512 threads. Block kt handles codes [kt*16, kt*16+16).
// Fragment order: E2h[((ds*64 + ktile)*64 + lane)*8 + j]
// lane -> (m=lane&15 = k-within-tile, d=ds*32 + (lane>>4)*8 + j)  (A-layout).
// ---------------------------------------------------------------------------
__global__ void vq_eprep(const float* __restrict__ e, unsigned short* __restrict__ E2h,
                         unsigned short* __restrict__ E2l, float* __restrict__ enorm,
                         float* __restrict__ sum_e_d) {
  __shared__ float ered[16][33];
  __shared__ float sumed[256];
  const int t  = threadIdx.x;
  const int kt = blockIdx.x;
  const int ds = t >> 6, l = t & 63;
  const int q  = l >> 4, m = l & 15;
  const int k  = kt * 16 + m;
  const int d0 = ds * 32 + q * 8;
  if (t < 256) sumed[t] = 0.0f;
  __syncthreads();

  const float* ep = e + (size_t)k * D_ + d0;
  const float4 v0 = *(const float4*)ep;
  const float4 v1 = *(const float4*)(ep + 4);
  const float vv[8] = {v0.x, v0.y, v0.z, v0.w, v1.x, v1.y, v1.z, v1.w};
  short hv[8], lv[8];
  float p = 0.0f;
  #pragma unroll
  for (int j = 0; j < 8; ++j) {
    const float f = vv[j];
    p += f * f;
    const unsigned short h = f2bf(f);
    hv[j] = (short)h;
    const float hf = __uint_as_float((unsigned int)h << 16);
    lv[j] = (short)f2bf(f - hf);
    atomicAdd(&sumed[d0 + j], f);
  }
  const size_t fi = ((size_t)(ds * 64 + kt)) * 64 + l;
  *(bf16x8*)(E2h + fi * 8) = *(bf16x8*)hv;
  *(bf16x8*)(E2l + fi * 8) = *(bf16x8*)lv;

  ered[m][ds * 4 + q] = p;
  __syncthreads();
  if (t < 16) {
    float s = 0.0f;
    #pragma unroll
    for (int i = 0; i < 32; ++i) s += ered[t][i];
    enorm[kt * 16 + t] = s;
  }
  if (t < 256) atomicAdd(&sum_e_d[t], sumed[t]);
}

// ---------------------------------------------------------------------------
// Fused argmin + gather. grid 512 (b x 16 hw-tiles of 64 n), 512 threads.
// Phase A: stage ALL 256 d of Z (hi/lo bf16 fragments) into LDS; one barrier.
// Phase B: each wave streams its 128-k range, NO barriers: 768 MFMAs,
//          128 coalesced global A-frag loads, 64 LDS B-frag reads.
// Phase C: per-n argmin reduce; counts; analytic diff^2 = ||z||^2 + dmin.
// Phase D: stage chosen e-rows into LDS (union over Z), write out coalesced.
// ---------------------------------------------------------------------------
__global__ __launch_bounds__(512, 2)
void vq_argmin3(const float* __restrict__ z, const float* __restrict__ e,
                const unsigned short* __restrict__ E2h, const unsigned short* __restrict__ E2l,
                const float* __restrict__ enorm_g,
                float* __restrict__ out, unsigned int* __restrict__ counts,
                float* __restrict__ sum_z_d, double* __restrict__ scald) {
  union SM {
    struct { unsigned short Zh[8][2048]; unsigned short Zl[8][2048]; } s;  // 64 KB
    float erow[64 * 257];                                                  // 65792 B
  };
  __shared__ SM sm;
  __shared__ float en[1024];
  __shared__ unsigned long long red[8][64];
  __shared__ float sumzd[256];
  __shared__ float zn2[64];
  __shared__ unsigned int kbuf[64];

  const int t  = threadIdx.x;
  const int nt = blockIdx.x;
  const int b   = nt >> 4;
  const int hw0 = (nt & 15) << 6;
  const int w = t >> 6, l = t & 63;
  const int quad = l >> 4;

  // staging identity
  const int slot  = t & 255;
  const int jh    = t >> 8;                            // 0/1 -> j = jh*4 + c
  const int squad = (slot >> 4) & 3;
  const int nloc  = ((slot >> 6) << 4) + (slot & 15);  // ntile*16 + n15
  const float* zb = z + (size_t)b * D_ * HW_ + hw0 + nloc;

  if (t < 256) sumzd[t] = 0.0f;
  if (t < 64)  zn2[t] = 0.0f;
  en[t] = enorm_g[t];
  en[t + 512] = enorm_g[t + 512];
  __syncthreads();

  // ---- Phase A: stage all of Z ----
  float zn2acc = 0.0f;
  #pragma unroll
  for (int ds = 0; ds < 8; ++ds) {
    const int dbase = ds * 32 + squad * 8 + jh * 4;
    float f[4];
    #pragma unroll
    for (int c = 0; c < 4; ++c) f[c] = zb[(size_t)(dbase + c) * HW_];
    short hv[4], lv[4];
    #pragma unroll
    for (int c = 0; c < 4; ++c) {
      zn2acc = fmaf(f[c], f[c], zn2acc);
      atomicAdd(&sumzd[dbase + c], f[c]);
      const unsigned short h = f2bf(f[c]);
      hv[c] = (short)h;
      lv[c] = (short)f2bf(f[c] - __uint_as_float((unsigned int)h << 16));
    }
    *(s16x4*)&sm.s.Zh[ds][slot * 8 + jh * 4] = *(s16x4*)hv;
    *(s16x4*)&sm.s.Zl[ds][slot * 8 + jh * 4] = *(s16x4*)lv;
  }
  atomicAdd(&zn2[nloc], zn2acc);
  __syncthreads();   // Z fragments + stats ready

  // ---- Phase B: barrier-free k-stream ----
  const bf16x8* __restrict__ Eh8 = (const bf16x8*)E2h;
  const bf16x8* __restrict__ El8 = (const bf16x8*)E2l;

  f32x4 acc[8][4];
  #pragma unroll
  for (int kt = 0; kt < 8; ++kt)
    #pragma unroll
    for (int ni = 0; ni < 4; ++ni) acc[kt][ni] = (f32x4)0.0f;

  #pragma unroll
  for (int ds = 0; ds < 8; ++ds) {
    bf16x8 Bh[4], Bl[4];
    #pragma unroll
    for (int ni = 0; ni < 4; ++ni) {
      Bh[ni] = *(const bf16x8*)&sm.s.Zh[ds][(ni * 64 + l) * 8];
      Bl[ni] = *(const bf16x8*)&sm.s.Zl[ds][(ni * 64 + l) * 8];
    }
    #pragma unroll
    for (int kt = 0; kt < 8; ++kt) {
      const size_t fi = ((size_t)(ds * 64 + w * 8 + kt)) * 64 + l;
      const bf16x8 Ah = Eh8[fi];
      const bf16x8 Al = El8[fi];
      #pragma unroll
      for (int ni = 0; ni < 4; ++ni) {
        f32x4 a = acc[kt][ni];
        a = __builtin_amdgcn_mfma_f32_16x16x32_bf16(Ah, Bh[ni], a, 0, 0, 0);
        a = __builtin_amdgcn_mfma_f32_16x16x32_bf16(Ah, Bl[ni], a, 0, 0, 0);
        a = __builtin_amdgcn_mfma_f32_16x16x32_bf16(Al, Bh[ni], a, 0, 0, 0);
        acc[kt][ni] = a;
      }
    }
  }

  // ---- Phase C: argmin reduce ----
  #pragma unroll
  for (int ni = 0; ni < 4; ++ni) {
    float bv = 3.0e38f;
    int   bk = 0;
    #pragma unroll
    for (int kt = 0; kt < 8; ++kt) {
      const f32x4 a = acc[kt][ni];
      #pragma unroll
      for (int r = 0; r < 4; ++r) {
        const int k = w * 128 + kt * 16 + quad * 4 + r;
        const float v = fmaf(-2.0f, a[r], en[k]);
        if (v < bv) { bv = v; bk = k; }     // k ascending => first-min tiebreak
      }
    }
    unsigned long long p = pack64(bv, bk);
    unsigned long long p2 = __shfl_down(p, 32, 64); if (p2 < p) p = p2;
    p2 = __shfl_down(p, 16, 64);                    if (p2 < p) p = p2;
    if (quad == 0) red[w][ni * 16 + (l & 15)] = p;
  }
  __syncthreads();

  if (t < 256) atomicAdd(&sum_z_d[t], sumzd[t]);
  if (t < 64) {
    unsigned long long m = red[0][t];
    #pragma unroll
    for (int i = 1; i < 8; ++i) { const unsigned long long c = red[i][t]; if (c < m) m = c; }
    const unsigned int k = (unsigned int)(m & 0xFFFFFFFFull);
    kbuf[t] = k;
    atomicAdd(&counts[k], 1u);
    const float dminv = unpack32((unsigned int)(m >> 32));
    const float z2    = zn2[t];
    float dsum = z2 + dminv;     // ||z_n - e_k||^2 (analytic)
    float zsum = z2;
    #pragma unroll
    for (int off = 32; off > 0; off >>= 1) {
      dsum += __shfl_down(dsum, off, 64);
      zsum += __shfl_down(zsum, off, 64);
    }
    if (t == 0) {
      atomicAdd(&scald[2], (double)dsum);
      atomicAdd(&scald[1], (double)zsum);
    }
  }
  __syncthreads();   // kbuf ready; Zh/Zl dead -> erow may overwrite

  // ---- Phase D: stage chosen e-rows, write out coalesced ----
  {
    const int r  = t >> 3;            // 0..63
    const int d0 = (t & 7) * 32;
    const unsigned int k = kbuf[r];
    const float* er = e + (size_t)k * D_ + d0;
    #pragma unroll
    for (int i = 0; i < 8; ++i) {
      const float4 f = *(const float4*)(er + i * 4);
      float* dst = &sm.erow[r * 257 + d0 + i * 4];
      dst[0] = f.x; dst[1] = f.y; dst[2] = f.z; dst[3] = f.w;
    }
  }
  __syncthreads();
  {
    float* ob = out + ((size_t)b * D_ + w * 32) * HW_ + hw0 + l;
    #pragma unroll
    for (int dd = 0; dd < 32; ++dd) {
      ob[(size_t)dd * HW_] = sm.erow[l * 257 + w * 32 + dd];
    }
  }
}

// ---------------------------------------------------------------------------
// finalize: loss, perplexity, mean_distance
// ---------------------------------------------------------------------------
__global__ void vq_final(const unsigned int* __restrict__ counts,
                         const float* __restrict__ enorm,
                         const float* __restrict__ sum_e_d, const float* __restrict__ sum_z_d,
                         const double* __restrict__ scald, float* __restrict__ out) {
  __shared__ float sred[4];
  const int t = threadIdx.x;
  float h = 0.0f;
  for (int i = t; i < K_; i += 256) {
    const float em = (float)counts[i] * (1.0f / (float)N_);
    h += em * logf(em + 1e-10f);
  }
  const float hs = blockReduceSum(h, sred);
  __syncthreads();
  const float dv = sum_z_d[t] * sum_e_d[t];
  const float dot = blockReduceSum(dv, sred);
  __syncthreads();
  float e2 = 0.0f;
  #pragma unroll
  for (int i = 0; i < 4; ++i) e2 += enorm[t + 256 * i];
  const float sume2 = blockReduceSum(e2, sred);
  if (t == 0) {
    const double loss = (double)(1.0f + BETA_) * scald[2] / (double)((size_t)N_ * D_);
    const float perp = expf(-hs);
    const double md = scald[1] / (double)N_ + (double)sume2 / (double)K_
                    - 2.0 * (double)dot / ((double)N_ * (double)K_);
    out[OUT0 + 0] = (float)loss;
    out[OUT0 + 1] = perp;
    out[OUT0 + 2] = (float)md;
  }
}

extern "C" void kernel_launch(void* const* d_in, const int* in_sizes, int n_in,
                              void* d_out, int out_size, void* d_ws, size_t ws_size,
                              hipStream_t stream) {
  const float* z = (const float*)d_in[0];        // [32,256,32,32]
  const float* e = (const float*)d_in[1];        // [1024,256]
  float* out = (float*)d_out;

  char* ws = (char*)d_ws;
  unsigned short* E2h = (unsigned short*)(ws + E2H_OFF);
  unsigned short* E2l = (unsigned short*)(ws + E2L_OFF);
  float* enorm   = (float*)(ws + ENORM_OFF);
  float* sum_e_d = (float*)(ws + SUMED_OFF);
  float* sum_z_d = (float*)(ws + SUMZD_OFF);
  unsigned int* counts = (unsigned int*)(ws + CNT_OFF);
  double* scald  = (double*)(ws + SCAL_OFF);

  hipMemsetAsync(ws + ZERO_OFF, 0x00, (size_t)ZERO_BYTES, stream);

  vq_eprep  <<<dim3(64),  dim3(512), 0, stream>>>(e, E2h, E2l, enorm, sum_e_d);
  vq_argmin3<<<dim3(512), dim3(512), 0, stream>>>(z, e, E2h, E2l, enorm, out, counts,
                                                  sum_z_d, scald);
  vq_final  <<<dim3(1),   dim3(256), 0, stream>>>(counts, enorm, sum_e_d, sum_z_d,
                                                  scald, out);
}